// Round 2
// baseline (981.797 us; speedup 1.0000x reference)
//
#include <hip/hip_runtime.h>

#define SLOPE 0.01f
#define BM 64
#define BN 64
#define BK 64
#define EPB 16

__device__ __forceinline__ float leaky(float x) { return x >= 0.f ? x : SLOPE * x; }

// ---------------------------------------------------------------------------
// Pass 0: find active edges (ntype[src]==2), compact their ids, mark recv dst.
// ---------------------------------------------------------------------------
__global__ __launch_bounds__(256) void k_build_active(
    const int* __restrict__ src, const int* __restrict__ dst,
    const int* __restrict__ ntype, int* __restrict__ list,
    int* __restrict__ cnt, float* __restrict__ recvf, int E)
{
    int e = blockIdx.x * 256 + threadIdx.x;
    if (e < E) {
        if (ntype[src[e]] == 2) {
            int p = atomicAdd(cnt, 1);
            list[p] = e;
            recvf[dst[e]] = 1.0f;   // concurrent same-value stores: fine
        }
    }
}

// ---------------------------------------------------------------------------
// T = h @ [We_src | We_dst]   (h: [M][128], We: [320][128], T: [M][256])
// ---------------------------------------------------------------------------
__global__ __launch_bounds__(256) void k_gemm_T(
    const float* __restrict__ A, const float* __restrict__ We,
    float* __restrict__ T, int M)
{
    __shared__ float As[BK][BM + 4];   // transposed [k][m], pad to kill store conflicts
    __shared__ float Bs[BK][BN];
    const int t  = threadIdx.x;
    const int m0 = blockIdx.x * BM;
    const int n0 = blockIdx.y * BN;
    const float* Wp = (n0 < 128) ? We : (We + 128 * 128);
    const int nb = (n0 < 128) ? n0 : (n0 - 128);

    const int tr = t >> 4;   // 0..15
    const int tc = t & 15;   // 0..15
    float acc[4][4] = {};

    for (int kt = 0; kt < 128; kt += BK) {
        #pragma unroll
        for (int p = 0; p < 4; ++p) {
            int f = t + p * 256;        // float4 id, 16 per row
            int am = f >> 4, ak4 = f & 15;
            int gm = m0 + am;
            float4 v = make_float4(0.f, 0.f, 0.f, 0.f);
            if (gm < M) v = *(const float4*)(A + (size_t)gm * 128 + kt + ak4 * 4);
            int kk = ak4 * 4;
            As[kk + 0][am] = v.x; As[kk + 1][am] = v.y;
            As[kk + 2][am] = v.z; As[kk + 3][am] = v.w;
        }
        #pragma unroll
        for (int p = 0; p < 4; ++p) {
            int f = t + p * 256;
            int bk = f >> 4, bn4 = f & 15;
            *(float4*)&Bs[bk][bn4 * 4] =
                *(const float4*)(Wp + (size_t)(kt + bk) * 128 + nb + bn4 * 4);
        }
        __syncthreads();
        #pragma unroll
        for (int kk = 0; kk < BK; ++kk) {
            float4 av = *(const float4*)&As[kk][tr * 4];
            float4 bv = *(const float4*)&Bs[kk][tc * 4];
            float a_[4] = {av.x, av.y, av.z, av.w};
            float b_[4] = {bv.x, bv.y, bv.z, bv.w};
            #pragma unroll
            for (int i = 0; i < 4; ++i)
                #pragma unroll
                for (int j = 0; j < 4; ++j)
                    acc[i][j] += a_[i] * b_[j];
        }
        __syncthreads();
    }
    #pragma unroll
    for (int i = 0; i < 4; ++i) {
        int gm = m0 + tr * 4 + i;
        if (gm < M)
            *(float4*)(T + (size_t)gm * 256 + n0 + tc * 4) =
                make_float4(acc[i][0], acc[i][1], acc[i][2], acc[i][3]);
    }
}

// ---------------------------------------------------------------------------
// out = leaky(h @ Wn[0:128] + red @ Wn[128:256]) * recv   ([M][128])
// NOT in-place safe: caller guarantees O does not alias H or R.
// ---------------------------------------------------------------------------
__global__ __launch_bounds__(256) void k_gemm_node(
    const float* __restrict__ H, const float* __restrict__ R,
    const float* __restrict__ Wn, const float* __restrict__ recvf,
    float* __restrict__ O, int M)
{
    __shared__ float As[BK][BM + 4];
    __shared__ float Bs[BK][BN];
    const int t  = threadIdx.x;
    const int m0 = blockIdx.x * BM;
    const int n0 = blockIdx.y * BN;

    const int tr = t >> 4;
    const int tc = t & 15;
    float acc[4][4] = {};

    for (int kt = 0; kt < 256; kt += BK) {
        const float* Ap = (kt < 128) ? (H + kt) : (R + (kt - 128));
        #pragma unroll
        for (int p = 0; p < 4; ++p) {
            int f = t + p * 256;
            int am = f >> 4, ak4 = f & 15;
            int gm = m0 + am;
            float4 v = make_float4(0.f, 0.f, 0.f, 0.f);
            if (gm < M) v = *(const float4*)(Ap + (size_t)gm * 128 + ak4 * 4);
            int kk = ak4 * 4;
            As[kk + 0][am] = v.x; As[kk + 1][am] = v.y;
            As[kk + 2][am] = v.z; As[kk + 3][am] = v.w;
        }
        #pragma unroll
        for (int p = 0; p < 4; ++p) {
            int f = t + p * 256;
            int bk = f >> 4, bn4 = f & 15;
            *(float4*)&Bs[bk][bn4 * 4] =
                *(const float4*)(Wn + (size_t)(kt + bk) * 128 + n0 + bn4 * 4);
        }
        __syncthreads();
        #pragma unroll
        for (int kk = 0; kk < BK; ++kk) {
            float4 av = *(const float4*)&As[kk][tr * 4];
            float4 bv = *(const float4*)&Bs[kk][tc * 4];
            float a_[4] = {av.x, av.y, av.z, av.w};
            float b_[4] = {bv.x, bv.y, bv.z, bv.w};
            #pragma unroll
            for (int i = 0; i < 4; ++i)
                #pragma unroll
                for (int j = 0; j < 4; ++j)
                    acc[i][j] += a_[i] * b_[j];
        }
        __syncthreads();
    }
    #pragma unroll
    for (int i = 0; i < 4; ++i) {
        int gm = m0 + tr * 4 + i;
        if (gm < M) {
            float rv = recvf[gm];
            float4 v = make_float4(leaky(acc[i][0]) * rv, leaky(acc[i][1]) * rv,
                                   leaky(acc[i][2]) * rv, leaky(acc[i][3]) * rv);
            *(float4*)(O + (size_t)gm * 128 + n0 + tc * 4) = v;
        }
    }
}

// ---------------------------------------------------------------------------
// Edge pass over compacted active edges:
//   msg = leaky(T[s][0:128] + T[d][128:256] + ef[e] @ We_ef);  red[d] += msg
// One wave per edge (2 output cols per lane), 16 edges per 256-thread block.
// ---------------------------------------------------------------------------
__global__ __launch_bounds__(256) void k_edge(
    const float* __restrict__ ef, const float* __restrict__ WeF,  // [64][128]
    const float* __restrict__ T, const int* __restrict__ list,
    const int* __restrict__ cntp, const int* __restrict__ src,
    const int* __restrict__ dst, float* __restrict__ red)
{
    __shared__ float Ws[64][128];
    __shared__ float efs[EPB][64];
    __shared__ int es[EPB], ss[EPB], dsh[EPB];

    const int t = threadIdx.x;
    const int cnt = *cntp;
    const int b0 = blockIdx.x * EPB;
    if (b0 >= cnt) return;

    #pragma unroll
    for (int p = 0; p < 8; ++p) {           // stage We_ef: 64x128 = 2048 float4
        int f = t + p * 256;
        int r = f >> 5, c4 = f & 31;
        *(float4*)&Ws[r][c4 * 4] = *(const float4*)(WeF + (size_t)r * 128 + c4 * 4);
    }
    if (t < EPB) {
        int pos = b0 + t;
        int e = (pos < cnt) ? list[pos] : -1;
        es[t] = e;
        ss[t] = (e >= 0) ? src[e] : 0;
        dsh[t] = (e >= 0) ? dst[e] : 0;
    }
    __syncthreads();
    {
        int i = t >> 4, k4 = t & 15;        // stage ef rows: 16 x 64
        int e = es[i];
        float4 v = make_float4(0.f, 0.f, 0.f, 0.f);
        if (e >= 0) v = *(const float4*)(ef + (size_t)e * 64 + k4 * 4);
        *(float4*)&efs[i][k4 * 4] = v;
    }
    __syncthreads();

    const int wv = t >> 6, lane = t & 63;
    #pragma unroll
    for (int ii = 0; ii < 4; ++ii) {
        int i = wv * 4 + ii;
        if (es[i] < 0) continue;
        int s = ss[i], d = dsh[i];
        float acc0 = T[(size_t)s * 256 + lane]      + T[(size_t)d * 256 + 128 + lane];
        float acc1 = T[(size_t)s * 256 + 64 + lane] + T[(size_t)d * 256 + 192 + lane];
        #pragma unroll
        for (int k4 = 0; k4 < 16; ++k4) {
            float4 e4 = *(const float4*)&efs[i][k4 * 4];  // broadcast read
            int k = k4 * 4;
            acc0 += e4.x * Ws[k][lane]      + e4.y * Ws[k + 1][lane]
                  + e4.z * Ws[k + 2][lane]  + e4.w * Ws[k + 3][lane];
            acc1 += e4.x * Ws[k][64 + lane]     + e4.y * Ws[k + 1][64 + lane]
                  + e4.z * Ws[k + 2][64 + lane] + e4.w * Ws[k + 3][64 + lane];
        }
        atomicAdd(&red[(size_t)d * 128 + lane],      leaky(acc0));
        atomicAdd(&red[(size_t)d * 128 + 64 + lane], leaky(acc1));
    }
}

// ---------------------------------------------------------------------------
extern "C" void kernel_launch(void* const* d_in, const int* in_sizes, int n_in,
                              void* d_out, int out_size, void* d_ws, size_t ws_size,
                              hipStream_t stream)
{
    const float* nf    = (const float*)d_in[0];
    const float* ef    = (const float*)d_in[1];
    const int*   src   = (const int*)d_in[2];
    const int*   dst   = (const int*)d_in[3];
    const int*   ntype = (const int*)d_in[4];
    const float* We[3] = {(const float*)d_in[5], (const float*)d_in[7], (const float*)d_in[9]};
    const float* Wn[3] = {(const float*)d_in[6], (const float*)d_in[8], (const float*)d_in[10]};

    const int N = in_sizes[0] / 128;
    const int E = in_sizes[1] / 64;

    float* T     = (float*)d_ws;             // N*256
    float* red   = T + (size_t)N * 256;      // N*128
    float* hA    = red + (size_t)N * 128;    // N*128
    float* recvf = hA + (size_t)N * 128;     // N
    int*   list  = (int*)(recvf + N);        // E
    int*   cnt   = list + E;                 // 1

    hipMemsetAsync(cnt, 0, sizeof(int), stream);
    hipMemsetAsync(recvf, 0, (size_t)N * sizeof(float), stream);
    k_build_active<<<(E + 255) / 256, 256, 0, stream>>>(src, dst, ntype, list, cnt, recvf, E);

    dim3 gT((N + BM - 1) / BM, 256 / BN);
    dim3 gN((N + BM - 1) / BM, 128 / BN);
    int  gE = (E + EPB - 1) / EPB;

    // Ping-pong so k_gemm_node never reads and writes the same buffer:
    // layer 0: nf    -> d_out
    // layer 1: d_out -> hA
    // layer 2: hA    -> d_out
    const float* h = nf;
    float* outs[3] = {(float*)d_out, hA, (float*)d_out};
    for (int l = 0; l < 3; ++l) {
        k_gemm_T<<<gT, 256, 0, stream>>>(h, We[l], T, N);
        hipMemsetAsync(red, 0, (size_t)N * 128 * sizeof(float), stream);
        k_edge<<<gE, 256, 0, stream>>>(ef, We[l] + 256 * 128, T, list, cnt, src, dst, red);
        k_gemm_node<<<gN, 256, 0, stream>>>(h, red, Wn[l], recvf, outs[l], N);
        h = outs[l];
    }
}

// Round 3
// 710.973 us; speedup vs baseline: 1.3809x; 1.3809x over previous
//
#include <hip/hip_runtime.h>

typedef unsigned short u16;
typedef short s16x8 __attribute__((ext_vector_type(8)));
typedef float f32x4 __attribute__((ext_vector_type(4)));

#define SLOPE 0.01f
#define EPB 16

__device__ __forceinline__ float leaky(float x) { return x >= 0.f ? x : SLOPE * x; }

__device__ __forceinline__ u16 f2b(float f) {          // round-to-nearest-even
    union { float f; unsigned u; } v; v.f = f;
    unsigned r = v.u + 0x7FFFu + ((v.u >> 16) & 1u);
    return (u16)(r >> 16);
}
__device__ __forceinline__ float b2f(u16 b) {
    union { unsigned u; float f; } v; v.u = ((unsigned)b) << 16; return v.f;
}

// ---------------------------------------------------------------------------
// Pass 0: find active edges (ntype[src]==2), compact their ids, mark recv dst.
// ---------------------------------------------------------------------------
__global__ __launch_bounds__(256) void k_build_active(
    const int* __restrict__ src, const int* __restrict__ dst,
    const int* __restrict__ ntype, int* __restrict__ list,
    int* __restrict__ cnt, float* __restrict__ recvf, int E)
{
    int e = blockIdx.x * 256 + threadIdx.x;
    if (e < E) {
        if (ntype[src[e]] == 2) {
            int p = atomicAdd(cnt, 1);
            list[p] = e;
            recvf[dst[e]] = 1.0f;
        }
    }
}

// ---------------------------------------------------------------------------
// fp32 -> bf16 bulk convert (n multiple of 4)
// ---------------------------------------------------------------------------
__global__ __launch_bounds__(256) void k_f2b(const float* __restrict__ in,
                                             u16* __restrict__ out, int n4)
{
    int i = blockIdx.x * 256 + threadIdx.x;
    if (i < n4) {
        float4 v = ((const float4*)in)[i];
        ushort4 o;
        o.x = f2b(v.x); o.y = f2b(v.y); o.z = f2b(v.z); o.w = f2b(v.w);
        ((ushort4*)out)[i] = o;
    }
}

// ---------------------------------------------------------------------------
// W [K][128] fp32 row-major  ->  WT [128][K] bf16 (n-major)
// ---------------------------------------------------------------------------
__global__ __launch_bounds__(256) void k_wt(const float* __restrict__ W,
                                            u16* __restrict__ WT, int K)
{
    int idx = blockIdx.x * 256 + threadIdx.x;
    if (idx < K * 128) {
        int k = idx >> 7, n = idx & 127;
        WT[n * K + k] = f2b(W[idx]);
    }
}

// ---------------------------------------------------------------------------
// T = h @ [We_src | We_dst]  via bf16 MFMA, fp32 accumulate.
// A: [M][128] bf16.  WT: [2][128 n][128 k] bf16.  T out: [M][256] bf16.
// block 256 = 4 waves (2x2), tile 128x128, BK=64.
// ---------------------------------------------------------------------------
__global__ __launch_bounds__(256) void k_gemm_T(
    const u16* __restrict__ A, const u16* __restrict__ WT,
    u16* __restrict__ T, int M)
{
    __shared__ u16 As[128][72];
    __shared__ u16 Bs[128][72];
    const int t = threadIdx.x;
    const int m0 = blockIdx.x * 128;
    const int sel = blockIdx.y;
    const u16* Wp = WT + (size_t)sel * 128 * 128;
    const int w = t >> 6, lane = t & 63, wm = w >> 1, wn = w & 1;
    f32x4 acc[4][4] = {};

    const int row = t >> 1, koff = (t & 1) * 32;
    const int gm_s = m0 + row;

    for (int kt = 0; kt < 128; kt += 64) {
        #pragma unroll
        for (int j = 0; j < 4; ++j) {
            int4 va = make_int4(0, 0, 0, 0);
            if (gm_s < M) va = *(const int4*)(A + (size_t)gm_s * 128 + kt + koff + j * 8);
            *(int4*)&As[row][koff + j * 8] = va;
            *(int4*)&Bs[row][koff + j * 8] =
                *(const int4*)(Wp + (size_t)row * 128 + kt + koff + j * 8);
        }
        __syncthreads();
        #pragma unroll
        for (int kf = 0; kf < 2; ++kf) {
            s16x8 a[4], b[4];
            #pragma unroll
            for (int mi = 0; mi < 4; ++mi)
                a[mi] = *(const s16x8*)&As[wm * 64 + mi * 16 + (lane & 15)][kf * 32 + (lane >> 4) * 8];
            #pragma unroll
            for (int ni = 0; ni < 4; ++ni)
                b[ni] = *(const s16x8*)&Bs[wn * 64 + ni * 16 + (lane & 15)][kf * 32 + (lane >> 4) * 8];
            #pragma unroll
            for (int mi = 0; mi < 4; ++mi)
                #pragma unroll
                for (int ni = 0; ni < 4; ++ni)
                    acc[mi][ni] = __builtin_amdgcn_mfma_f32_16x16x32_bf16(
                        a[mi], b[ni], acc[mi][ni], 0, 0, 0);
        }
        __syncthreads();
    }
    const int lr = (lane >> 4) * 4, lc = lane & 15;
    const int ncol0 = sel * 128 + wn * 64;
    #pragma unroll
    for (int mi = 0; mi < 4; ++mi) {
        #pragma unroll
        for (int r = 0; r < 4; ++r) {
            int gm = m0 + wm * 64 + mi * 16 + lr + r;
            if (gm < M) {
                #pragma unroll
                for (int ni = 0; ni < 4; ++ni)
                    T[(size_t)gm * 256 + ncol0 + ni * 16 + lc] = f2b(acc[mi][ni][r]);
            }
        }
    }
}

// ---------------------------------------------------------------------------
// out = leaky([H | R] @ Wn) * recv.  H bf16 [M][128], R fp32 [M][128],
// WT [128 n][256 k] bf16.  fin=1 -> write fp32 to O32, else bf16 to O16.
// ---------------------------------------------------------------------------
__global__ __launch_bounds__(256) void k_gemm_node(
    const u16* __restrict__ H, const float* __restrict__ R,
    const u16* __restrict__ WT, const float* __restrict__ recvf,
    u16* __restrict__ O16, float* __restrict__ O32, int fin, int M)
{
    __shared__ u16 As[128][72];
    __shared__ u16 Bs[128][72];
    const int t = threadIdx.x;
    const int m0 = blockIdx.x * 128;
    const int w = t >> 6, lane = t & 63, wm = w >> 1, wn = w & 1;
    f32x4 acc[4][4] = {};

    const int row = t >> 1, koff = (t & 1) * 32;
    const int gm_s = m0 + row;

    for (int kt = 0; kt < 256; kt += 64) {
        if (kt < 128) {
            #pragma unroll
            for (int j = 0; j < 4; ++j) {
                int4 va = make_int4(0, 0, 0, 0);
                if (gm_s < M) va = *(const int4*)(H + (size_t)gm_s * 128 + kt + koff + j * 8);
                *(int4*)&As[row][koff + j * 8] = va;
            }
        } else {
            #pragma unroll
            for (int j = 0; j < 8; ++j) {
                float4 v = make_float4(0.f, 0.f, 0.f, 0.f);
                if (gm_s < M) v = *(const float4*)(R + (size_t)gm_s * 128 + (kt - 128) + koff + j * 4);
                ushort4 o;
                o.x = f2b(v.x); o.y = f2b(v.y); o.z = f2b(v.z); o.w = f2b(v.w);
                *(ushort4*)&As[row][koff + j * 4] = o;
            }
        }
        #pragma unroll
        for (int j = 0; j < 4; ++j)
            *(int4*)&Bs[row][koff + j * 8] =
                *(const int4*)(WT + (size_t)row * 256 + kt + koff + j * 8);
        __syncthreads();
        #pragma unroll
        for (int kf = 0; kf < 2; ++kf) {
            s16x8 a[4], b[4];
            #pragma unroll
            for (int mi = 0; mi < 4; ++mi)
                a[mi] = *(const s16x8*)&As[wm * 64 + mi * 16 + (lane & 15)][kf * 32 + (lane >> 4) * 8];
            #pragma unroll
            for (int ni = 0; ni < 4; ++ni)
                b[ni] = *(const s16x8*)&Bs[wn * 64 + ni * 16 + (lane & 15)][kf * 32 + (lane >> 4) * 8];
            #pragma unroll
            for (int mi = 0; mi < 4; ++mi)
                #pragma unroll
                for (int ni = 0; ni < 4; ++ni)
                    acc[mi][ni] = __builtin_amdgcn_mfma_f32_16x16x32_bf16(
                        a[mi], b[ni], acc[mi][ni], 0, 0, 0);
        }
        __syncthreads();
    }
    const int lr = (lane >> 4) * 4, lc = lane & 15;
    #pragma unroll
    for (int mi = 0; mi < 4; ++mi) {
        #pragma unroll
        for (int r = 0; r < 4; ++r) {
            int gm = m0 + wm * 64 + mi * 16 + lr + r;
            if (gm < M) {
                float rv = recvf[gm];
                #pragma unroll
                for (int ni = 0; ni < 4; ++ni) {
                    float val = leaky(acc[mi][ni][r]) * rv;
                    size_t o = (size_t)gm * 128 + wn * 64 + ni * 16 + lc;
                    if (fin) O32[o] = val;
                    else     O16[o] = f2b(val);
                }
            }
        }
    }
}

// ---------------------------------------------------------------------------
// Edge pass over compacted active edges (T is bf16 now):
//   msg = leaky(T[s][0:128] + T[d][128:256] + ef[e] @ We_ef);  red[d] += msg
// ---------------------------------------------------------------------------
__global__ __launch_bounds__(256) void k_edge(
    const float* __restrict__ ef, const float* __restrict__ WeF,  // [64][128] fp32
    const u16* __restrict__ T16, const int* __restrict__ list,
    const int* __restrict__ cntp, const int* __restrict__ src,
    const int* __restrict__ dst, float* __restrict__ red)
{
    __shared__ float Ws[64][128];
    __shared__ float efs[EPB][64];
    __shared__ int es[EPB], ss[EPB], dsh[EPB];

    const int t = threadIdx.x;
    const int cnt = *cntp;
    const int b0 = blockIdx.x * EPB;
    if (b0 >= cnt) return;

    #pragma unroll
    for (int p = 0; p < 8; ++p) {
        int f = t + p * 256;
        int r = f >> 5, c4 = f & 31;
        *(float4*)&Ws[r][c4 * 4] = *(const float4*)(WeF + (size_t)r * 128 + c4 * 4);
    }
    if (t < EPB) {
        int pos = b0 + t;
        int e = (pos < cnt) ? list[pos] : -1;
        es[t] = e;
        ss[t] = (e >= 0) ? src[e] : 0;
        dsh[t] = (e >= 0) ? dst[e] : 0;
    }
    __syncthreads();
    {
        int i = t >> 4, k4 = t & 15;
        int e = es[i];
        float4 v = make_float4(0.f, 0.f, 0.f, 0.f);
        if (e >= 0) v = *(const float4*)(ef + (size_t)e * 64 + k4 * 4);
        *(float4*)&efs[i][k4 * 4] = v;
    }
    __syncthreads();

    const int wv = t >> 6, lane = t & 63;
    #pragma unroll
    for (int ii = 0; ii < 4; ++ii) {
        int i = wv * 4 + ii;
        if (es[i] < 0) continue;
        int s = ss[i], d = dsh[i];
        float acc0 = b2f(T16[(size_t)s * 256 + lane])      + b2f(T16[(size_t)d * 256 + 128 + lane]);
        float acc1 = b2f(T16[(size_t)s * 256 + 64 + lane]) + b2f(T16[(size_t)d * 256 + 192 + lane]);
        #pragma unroll
        for (int k4 = 0; k4 < 16; ++k4) {
            float4 e4 = *(const float4*)&efs[i][k4 * 4];
            int k = k4 * 4;
            acc0 += e4.x * Ws[k][lane]      + e4.y * Ws[k + 1][lane]
                  + e4.z * Ws[k + 2][lane]  + e4.w * Ws[k + 3][lane];
            acc1 += e4.x * Ws[k][64 + lane]     + e4.y * Ws[k + 1][64 + lane]
                  + e4.z * Ws[k + 2][64 + lane] + e4.w * Ws[k + 3][64 + lane];
        }
        atomicAdd(&red[(size_t)d * 128 + lane],      leaky(acc0));
        atomicAdd(&red[(size_t)d * 128 + 64 + lane], leaky(acc1));
    }
}

// ---------------------------------------------------------------------------
extern "C" void kernel_launch(void* const* d_in, const int* in_sizes, int n_in,
                              void* d_out, int out_size, void* d_ws, size_t ws_size,
                              hipStream_t stream)
{
    const float* nf    = (const float*)d_in[0];
    const float* ef    = (const float*)d_in[1];
    const int*   src   = (const int*)d_in[2];
    const int*   dst   = (const int*)d_in[3];
    const int*   ntype = (const int*)d_in[4];
    const float* We[3] = {(const float*)d_in[5], (const float*)d_in[7], (const float*)d_in[9]};
    const float* Wn[3] = {(const float*)d_in[6], (const float*)d_in[8], (const float*)d_in[10]};

    const int N = in_sizes[0] / 128;
    const int E = in_sizes[1] / 64;

    // workspace layout: 16B-aligned bf16 arrays first
    u16* T16 = (u16*)d_ws;                       // N*256
    u16* hb0 = T16 + (size_t)N * 256;            // N*128
    u16* hb1 = hb0 + (size_t)N * 128;            // N*128
    u16* WTe = hb1 + (size_t)N * 128;            // 3 * 2 * 128*128
    u16* WTn = WTe + 3 * 2 * 128 * 128;          // 3 * 128*256
    float* red   = (float*)(WTn + 3 * 128 * 256);// N*128 fp32
    float* recvf = red + (size_t)N * 128;        // N
    int*   list  = (int*)(recvf + N);            // E
    int*   cnt   = list + E;                     // 1

    hipMemsetAsync(cnt, 0, sizeof(int), stream);
    hipMemsetAsync(recvf, 0, (size_t)N * sizeof(float), stream);
    k_build_active<<<(E + 255) / 256, 256, 0, stream>>>(src, dst, ntype, list, cnt, recvf, E);

    // nf -> bf16
    k_f2b<<<(N * 128 / 4 + 255) / 256, 256, 0, stream>>>(nf, hb0, N * 128 / 4);

    // per-layer weight transposes (bf16)
    for (int l = 0; l < 3; ++l) {
        k_wt<<<(128 * 128 + 255) / 256, 256, 0, stream>>>(We[l],             WTe + (size_t)l * 2 * 16384,         128);
        k_wt<<<(128 * 128 + 255) / 256, 256, 0, stream>>>(We[l] + 128 * 128, WTe + (size_t)l * 2 * 16384 + 16384, 128);
        k_wt<<<(256 * 128 + 255) / 256, 256, 0, stream>>>(Wn[l],             WTn + (size_t)l * 32768,             256);
    }

    dim3 gT((N + 127) / 128, 2);
    dim3 gN((N + 127) / 128, 1);
    int  gE = (E + EPB - 1) / EPB;

    const u16* hIn[3]  = {hb0, hb1, hb0};
    u16*       hOut[3] = {hb1, hb0, hb1};
    for (int l = 0; l < 3; ++l) {
        int fin = (l == 2);
        k_gemm_T<<<gT, 256, 0, stream>>>(hIn[l], WTe + (size_t)l * 2 * 16384, T16, N);
        hipMemsetAsync(red, 0, (size_t)N * 128 * sizeof(float), stream);
        k_edge<<<gE, 256, 0, stream>>>(ef, We[l] + 256 * 128, T16, list, cnt, src, dst, red);
        k_gemm_node<<<gN, 256, 0, stream>>>(hIn[l], red, WTn + (size_t)l * 32768,
                                            recvf, hOut[l], (float*)d_out, fin, N);
    }
}